// Round 1
// baseline (153.460 us; speedup 1.0000x reference)
//
#include <hip/hip_runtime.h>

// Problem constants (match reference)
#define VOCABN 100
#define EMBEDN 16
#define STATEN 7
#define OUTN   10
#define BATCHN 4096
#define SEQT   512

// ---------------------------------------------------------------------------
// Fast device math: raw v_exp_f32 / v_rcp_f32 (both handle inf/0 saturation,
// which makes the sigmoid/tanh formulations below exact at the extremes).
// ---------------------------------------------------------------------------
__device__ __forceinline__ float fast_exp2(float x) {
    float r; asm("v_exp_f32 %0, %1" : "=v"(r) : "v"(x)); return r;
}
__device__ __forceinline__ float fast_rcp(float x) {
    float r; asm("v_rcp_f32 %0, %1" : "=v"(r) : "v"(x)); return r;
}
#define L2E 1.44269504088896340736f

__device__ __forceinline__ float sigmoid_f(float x) {
    // 1/(1+e^-x); e^-x -> inf => rcp -> 0 (correct), e^-x -> 0 => 1 (correct)
    return fast_rcp(1.0f + fast_exp2(-L2E * x));
}
__device__ __forceinline__ float tanh_f(float x) {
    // 1 - 2/(e^{2x}+1); saturates to +/-1 correctly for |x| large
    return 1.0f - 2.0f * fast_rcp(1.0f + fast_exp2(2.0f * L2E * x));
}

// ---------------------------------------------------------------------------
// Kernel A: embW[v][slot][gate] = b[gate*7+s] + sum_e emb[v][e]*W[e][gate*7+s]
// with bank-rotation swizzle slot = (s + v) & 7 (pad state s=7 -> zeros).
// 100 x 8 x 4 floats = 12.8 KB into d_ws.
// ---------------------------------------------------------------------------
__global__ void embw_kernel(const float* __restrict__ emb,
                            const float* __restrict__ W,
                            const float* __restrict__ b,
                            float* __restrict__ embw) {
    int v = blockIdx.x;          // vocab id
    int j = threadIdx.x;         // 0..31
    int s = j >> 2, gate = j & 3;
    float val = 0.0f;
    if (s < STATEN) {
        int col = gate * STATEN + s;      // column in [0,28)
        val = b[col];
        #pragma unroll
        for (int e = 0; e < EMBEDN; ++e)
            val = fmaf(emb[v * EMBEDN + e], W[e * 28 + col], val);
    }
    embw[v * 32 + ((s + v) & 7) * 4 + gate] = val;
}

// ---------------------------------------------------------------------------
// Kernel B: fused LSTM recurrence + dense + softmax.
// 64 threads/block = 1 wave = 8 groups of 8 lanes; group g handles batch
// blockIdx.x*8+g; lane s owns state s (s=7 is a pad lane).
// LDS: embW table (12.8KB), token stage (8x516 ints, padded stride for
// conflict-free per-t reads), h ring buffer (8 slots x 8 states per group).
// Every 8 timesteps the lanes transpose roles: lane s computes dense+softmax
// for buffered timestep t-7+s (all 64 lanes busy, writes 320B/group chunks).
// ---------------------------------------------------------------------------
__global__ void __launch_bounds__(64)
lstm_kernel(const int*   __restrict__ tokens,
            const float* __restrict__ embw,
            const float* __restrict__ U,
            const float* __restrict__ Wd,
            const float* __restrict__ bd,
            float* __restrict__ out) {
    __shared__ float embW_s[VOCABN * 32];   // [v][slot][gate], swizzled
    __shared__ int   tok_s[8 * 516];        // stride 516: groups hit distinct banks
    __shared__ float hbuf[8 * 68];          // per group: 8 slots * 8 + 4 pad (16B-aligned rows)

    const int tid = threadIdx.x;
    const int g = tid >> 3, s = tid & 7;
    const int b0 = blockIdx.x * 8;

    // ---- stage embW table (800 float4, coalesced) ----
    for (int i = tid; i < VOCABN * 8; i += 64)
        ((float4*)embW_s)[i] = ((const float4*)embw)[i];
    // ---- stage tokens: 8 rows x 128 int4 ----
    for (int i = tid; i < 8 * 128; i += 64) {
        int r = i >> 7, c4 = i & 127;
        int4 v = ((const int4*)(tokens + (size_t)(b0 + r) * SEQT))[c4];
        *((int4*)&tok_s[r * 516 + c4 * 4]) = v;
    }
    // ---- zero h ring buffer (h_{-1} = 0, read from slot 7 at t=0) ----
    for (int i = tid; i < 8 * 68; i += 64) hbuf[i] = 0.0f;
    __syncthreads();

    // ---- per-lane weights in registers ----
    const int ss = (s < STATEN) ? s : 6;     // pad lane duplicates state 6 (never read)
    float Ur0[7], Ur1[7], Ur2[7], Ur3[7];
    #pragma unroll
    for (int j = 0; j < 7; ++j) {
        Ur0[j] = U[j * 28 + 0 * 7 + ss];
        Ur1[j] = U[j * 28 + 1 * 7 + ss];
        Ur2[j] = U[j * 28 + 2 * 7 + ss];
        Ur3[j] = U[j * 28 + 3 * 7 + ss];
    }
    float Wdr[7][10];
    #pragma unroll
    for (int j = 0; j < 7; ++j)
        #pragma unroll
        for (int o = 0; o < OUTN; ++o) Wdr[j][o] = Wd[j * 10 + o];
    float bdr[10];
    #pragma unroll
    for (int o = 0; o < OUTN; ++o) bdr[o] = bd[o];

    const int*  trow = &tok_s[g * 516];
    float*      hrow = &hbuf[g * 68];
    float*      outg = out + (size_t)(b0 + g) * SEQT * OUTN;
    float c = 0.0f;

    for (int t = 0; t < SEQT; ++t) {
        // previous h (written by the whole group last step; same-wave LDS is in-order)
        const int slotp = (t + 7) & 7;
        float4 ha  = *((const float4*)&hrow[slotp * 8]);
        float4 hb2 = *((const float4*)&hrow[slotp * 8 + 4]);
        const float hj[7] = {ha.x, ha.y, ha.z, ha.w, hb2.x, hb2.y, hb2.z};

        // z = embW[token] (x@W + b, swizzle-gathered) + h@U
        const int tok = trow[t];
        float4 zz = *((const float4*)&embW_s[tok * 32 + ((s + tok) & 7) * 4]);
        float z0 = zz.x, z1 = zz.y, z2 = zz.z, z3 = zz.w;
        #pragma unroll
        for (int j = 0; j < 7; ++j) {
            z0 = fmaf(hj[j], Ur0[j], z0);
            z1 = fmaf(hj[j], Ur1[j], z1);
            z2 = fmaf(hj[j], Ur2[j], z2);
            z3 = fmaf(hj[j], Ur3[j], z3);
        }
        // gates (Keras order i,f,g,o; forget bias already folded into embW via b)
        float gi = sigmoid_f(z0), gf = sigmoid_f(z1);
        float gg = tanh_f(z2),    go = sigmoid_f(z3);
        c = fmaf(gf, c, gi * gg);
        float h = go * tanh_f(c);
        hrow[(t & 7) * 8 + s] = h;

        if ((t & 7) == 7) {
            __syncthreads();   // single-wave block: essentially a waitcnt
            // lane s -> dense+softmax for timestep ts = t-7+s using slot s
            float4 h03 = *((const float4*)&hrow[s * 8]);
            float4 h47 = *((const float4*)&hrow[s * 8 + 4]);
            const float hh[7] = {h03.x, h03.y, h03.z, h03.w, h47.x, h47.y, h47.z};
            float lg[10];
            #pragma unroll
            for (int o = 0; o < OUTN; ++o) {
                float a = bdr[o];
                #pragma unroll
                for (int j = 0; j < 7; ++j) a = fmaf(hh[j], Wdr[j][o], a);
                lg[o] = a;
            }
            float m = lg[0];
            #pragma unroll
            for (int o = 1; o < OUTN; ++o) m = fmaxf(m, lg[o]);
            float e[10], sum = 0.0f;
            #pragma unroll
            for (int o = 0; o < OUTN; ++o) { e[o] = fast_exp2((lg[o] - m) * L2E); sum += e[o]; }
            float r = fast_rcp(sum);
            float* op = outg + (size_t)(t - 7 + s) * OUTN;   // 8B-aligned
            ((float2*)op)[0] = make_float2(e[0] * r, e[1] * r);
            ((float2*)op)[1] = make_float2(e[2] * r, e[3] * r);
            ((float2*)op)[2] = make_float2(e[4] * r, e[5] * r);
            ((float2*)op)[3] = make_float2(e[6] * r, e[7] * r);
            ((float2*)op)[4] = make_float2(e[8] * r, e[9] * r);
            __syncthreads(); // cheap WAR guard before slot 0 is overwritten at t+1
        }
    }
}

// ---------------------------------------------------------------------------
// Launch: inputs in setup_inputs() order:
// 0 tokens(int32 B*T) 1 emb 2 W 3 U 4 b 5 Wd 6 bd ; out = f32 B*T*10
// d_ws: first 12800 bytes hold the precomputed embW table (rewritten every
// call by embw_kernel -> deterministic, poison-safe).
// ---------------------------------------------------------------------------
extern "C" void kernel_launch(void* const* d_in, const int* in_sizes, int n_in,
                              void* d_out, int out_size, void* d_ws, size_t ws_size,
                              hipStream_t stream) {
    const int*   tokens = (const int*)d_in[0];
    const float* emb    = (const float*)d_in[1];
    const float* W      = (const float*)d_in[2];
    const float* U      = (const float*)d_in[3];
    const float* b      = (const float*)d_in[4];
    const float* Wd     = (const float*)d_in[5];
    const float* bd     = (const float*)d_in[6];
    float* out  = (float*)d_out;
    float* embw = (float*)d_ws;   // needs 12800 B of scratch

    embw_kernel<<<dim3(VOCABN), dim3(32), 0, stream>>>(emb, W, b, embw);
    lstm_kernel<<<dim3(BATCHN / 8), dim3(64), 0, stream>>>(tokens, embw, U, Wd, bd, out);
}

// Round 2
// 134.701 us; speedup vs baseline: 1.1393x; 1.1393x over previous
//
#include <hip/hip_runtime.h>

// Problem constants (match reference)
#define VOCABN 100
#define EMBEDN 16
#define STATEN 7
#define OUTN   10
#define BATCHN 4096
#define SEQT   512
#define L2E 1.44269504088896340736f

// ---------------------------------------------------------------------------
// Fast device math (v_exp_f32 / v_rcp_f32 saturate correctly at inf/0).
// rcp_nr adds one Newton step: near-exact division for the gate nonlinearities
// (accuracy insurance: FMA order changed vs round-1, buy back margin).
// ---------------------------------------------------------------------------
__device__ __forceinline__ float fexp2(float x){ float r; asm("v_exp_f32 %0, %1":"=v"(r):"v"(x)); return r; }
__device__ __forceinline__ float frcp (float x){ float r; asm("v_rcp_f32 %0, %1":"=v"(r):"v"(x)); return r; }
__device__ __forceinline__ float rcp_nr(float d){ float r = frcp(d); return r * __builtin_fmaf(-d, r, 2.0f); }
__device__ __forceinline__ float sigm  (float x){ return rcp_nr(1.0f + fexp2(-L2E * x)); }
__device__ __forceinline__ float tanh_f(float x){ return __builtin_fmaf(-2.0f, rcp_nr(1.0f + fexp2(2.0f * L2E * x)), 1.0f); }

// ---------------------------------------------------------------------------
// DPP cross-lane (VALU-latency, no LDS). Chains sit at strided (parity)
// positions inside a 16-lane DPP row so quad_perm[2,3,0,1] (lane^2) and
// row_ror:4/8/12 (even rotations) never mix the two chains sharing a row.
// ---------------------------------------------------------------------------
#define DPP_QP    0x4E    // quad_perm [2,3,0,1] == lane ^= 2 (involution)
#define DPP_ROR4  0x124
#define DPP_ROR8  0x128
#define DPP_ROR12 0x12C

template<int C> __device__ __forceinline__ int dppi(int x){
    return __builtin_amdgcn_update_dpp(0, x, C, 0xF, 0xF, true);
}
template<int C> __device__ __forceinline__ float dppf(float x){
    return __int_as_float(__builtin_amdgcn_update_dpp(0, __float_as_int(x), C, 0xF, 0xF, true));
}

// ---------------------------------------------------------------------------
// Kernel A: embW[v][slot][gate] = b[g*7+s] + sum_e emb[v][e]*W[e][g*7+s]
// slot = (s + v) & 7 bank-rotation swizzle; pad state s=7 -> zeros.
// ---------------------------------------------------------------------------
__global__ void embw_kernel(const float* __restrict__ emb,
                            const float* __restrict__ W,
                            const float* __restrict__ b,
                            float* __restrict__ embw) {
    int v = blockIdx.x;
    int jj = threadIdx.x;            // 0..31
    int s = jj >> 2, gate = jj & 3;
    float val = 0.0f;
    if (s < STATEN) {
        int col = gate * STATEN + s;
        val = b[col];
        #pragma unroll
        for (int e = 0; e < EMBEDN; ++e)
            val = fmaf(emb[v * EMBEDN + e], W[e * 28 + col], val);
    }
    embw[v * 32 + ((s + v) & 7) * 4 + gate] = val;
}

// ---------------------------------------------------------------------------
// Kernel B: fused LSTM + dense + softmax, barrier-free main loop.
// 64 threads = 1 wave = 4 DPP rows x 2 interleaved chains = 8 chains/block.
// Lane (row, parity, j=pos>>1) owns state j (j=7 pad) of chain row*2+parity.
// Per step: 7 DPP movs broadcast h within the chain; sigma (who lands where)
// is discovered at init by running lane indices through the same DPP net,
// and U/Wd coefficients are loaded pre-permuted -> zero runtime fixup.
// embW row + tokens prefetched from LDS 1-2 steps ahead (off critical path).
// Dense+softmax: lane j captures the full broadcast h-vector at t%8==j+1,
// flush every 8 steps, no LDS, no barriers.
// ---------------------------------------------------------------------------
__global__ void __launch_bounds__(64, 1)
lstm_kernel(const int*   __restrict__ tokens,
            const float* __restrict__ embw,
            const float* __restrict__ U,
            const float* __restrict__ Wd,
            const float* __restrict__ bdv,
            float* __restrict__ out) {
    __shared__ float embW_s[VOCABN * 32];   // 12.8 KB, swizzled rows
    __shared__ int   tok_s[8 * 516];        // stride 516 (bank 4-rotation), +2 pad entries

    const int L  = threadIdx.x;
    const int b0 = blockIdx.x * 8;

    // ---- stage embW (800 float4, coalesced) ----
    for (int i = L; i < VOCABN * 8; i += 64)
        ((float4*)embW_s)[i] = ((const float4*)embw)[i];
    // ---- stage tokens: 8 rows x 128 int4 ----
    for (int i = L; i < 8 * 128; i += 64) {
        int r = i >> 7, c4 = i & 127;
        int4 v = ((const int4*)(tokens + (size_t)(b0 + r) * SEQT))[c4];
        *((int4*)&tok_s[r * 516 + c4 * 4]) = v;
    }
    if (L < 8) { tok_s[L * 516 + 512] = 0; tok_s[L * 516 + 513] = 0; }
    __syncthreads();

    const int pos = L & 15;
    const int j   = pos >> 1;                 // owned state / group-pos (7 = pad)
    const int ch  = (L >> 4) * 2 + (pos & 1); // chain within block, 0..7

    // ---- sigma discovery: run lane group-pos through the exact DPP net ----
    int sg[8];
    sg[0] = j;
    sg[1] = dppi<DPP_QP   >(sg[0]);
    sg[2] = dppi<DPP_ROR4 >(sg[0]);
    sg[3] = dppi<DPP_ROR4 >(sg[1]);
    sg[4] = dppi<DPP_ROR8 >(sg[0]);
    sg[5] = dppi<DPP_ROR8 >(sg[1]);
    sg[6] = dppi<DPP_ROR12>(sg[0]);
    sg[7] = dppi<DPP_ROR12>(sg[1]);

    // ---- per-lane permuted weights (one-time uncoalesced gathers, L2-hot) ----
    float Uc[4][8];
    #pragma unroll
    for (int k = 0; k < 8; ++k) {
        int s = sg[k];
        bool vld = (s < STATEN) && (j < STATEN);
        #pragma unroll
        for (int g = 0; g < 4; ++g)
            Uc[g][k] = vld ? U[s * 28 + g * 7 + j] : 0.0f;
    }
    float Wdc[8][10];
    #pragma unroll
    for (int k = 0; k < 8; ++k) {
        int s = sg[k];
        #pragma unroll
        for (int o = 0; o < OUTN; ++o)
            Wdc[k][o] = (s < STATEN) ? Wd[s * 10 + o] : 0.0f;
    }
    float bdr[10];
    #pragma unroll
    for (int o = 0; o < OUTN; ++o) bdr[o] = bdv[o];

    const int* trow = &tok_s[ch * 516];
    float* outp = out + ((size_t)(b0 + ch) * SEQT + j) * OUTN;

    float hh[8];
    #pragma unroll
    for (int k = 0; k < 8; ++k) hh[k] = 0.0f;

    // dense + softmax flush for the octet ending before the current step
    auto flush = [&]() {
        float lg[10];
        #pragma unroll
        for (int o = 0; o < OUTN; ++o) {
            float a = bdr[o];
            #pragma unroll
            for (int k = 0; k < 8; ++k) a = __builtin_fmaf(hh[k], Wdc[k][o], a);
            lg[o] = a;
        }
        float m = lg[0];
        #pragma unroll
        for (int o = 1; o < OUTN; ++o) m = fmaxf(m, lg[o]);
        float e[10], sum = 0.0f;
        #pragma unroll
        for (int o = 0; o < OUTN; ++o) { e[o] = fexp2(L2E * (lg[o] - m)); sum += e[o]; }
        float rs = frcp(sum);
        float2* op = (float2*)outp;
        op[0] = make_float2(e[0] * rs, e[1] * rs);
        op[1] = make_float2(e[2] * rs, e[3] * rs);
        op[2] = make_float2(e[4] * rs, e[5] * rs);
        op[3] = make_float2(e[6] * rs, e[7] * rs);
        op[4] = make_float2(e[8] * rs, e[9] * rs);
        outp += 8 * OUTN;
    };

    // ---- prefetch prologue ----
    int tk0 = trow[0];
    int tkn = trow[1];
    float4 pf = *(const float4*)&embW_s[tk0 * 32 + (((j + tk0) & 7) << 2)];

    float c = 0.0f, h = 0.0f;

    for (int t8 = 0; t8 < SEQT; t8 += 8) {
        #pragma unroll
        for (int u = 0; u < 8; ++u) {
            // prefetch: token t+2, embW row t+1 (uses token fetched last iter)
            int tk2 = trow[t8 + u + 2];
            float4 pfn = *(const float4*)&embW_s[tkn * 32 + (((j + tkn) & 7) << 2)];

            // broadcast h_{t-1} across the 8-lane chain (7 DPP movs)
            float r0 = h;
            float r1 = dppf<DPP_QP   >(r0);
            float r2 = dppf<DPP_ROR4 >(r0);
            float r3 = dppf<DPP_ROR4 >(r1);
            float r4 = dppf<DPP_ROR8 >(r0);
            float r5 = dppf<DPP_ROR8 >(r1);
            float r6 = dppf<DPP_ROR12>(r0);
            float r7 = dppf<DPP_ROR12>(r1);

            // lane j captures the full h vector of timestep t-1 when t%8==j+1
            bool cap = (j == ((u + 7) & 7));
            hh[0] = cap ? r0 : hh[0];
            hh[1] = cap ? r1 : hh[1];
            hh[2] = cap ? r2 : hh[2];
            hh[3] = cap ? r3 : hh[3];
            hh[4] = cap ? r4 : hh[4];
            hh[5] = cap ? r5 : hh[5];
            hh[6] = cap ? r6 : hh[6];
            hh[7] = cap ? r7 : hh[7];

            if (u == 0 && t8 > 0) flush();   // uniform branch, once per octet

            // z = embW[tok] + h @ U   (coefficients pre-permuted by sigma)
            float z0 = pf.x, z1 = pf.y, z2 = pf.z, z3 = pf.w;
            #define ZK(k, rk) \
                z0 = __builtin_fmaf(rk, Uc[0][k], z0); \
                z1 = __builtin_fmaf(rk, Uc[1][k], z1); \
                z2 = __builtin_fmaf(rk, Uc[2][k], z2); \
                z3 = __builtin_fmaf(rk, Uc[3][k], z3);
            ZK(0, r0) ZK(1, r1) ZK(2, r2) ZK(3, r3)
            ZK(4, r4) ZK(5, r5) ZK(6, r6) ZK(7, r7)
            #undef ZK

            // gates (Keras order i,f,g,o; forget bias folded into embW)
            float gi = sigm(z0), gf = sigm(z1);
            float gg = tanh_f(z2), go = sigm(z3);
            c = __builtin_fmaf(gf, c, gi * gg);
            h = go * tanh_f(c);

            pf = pfn; tkn = tk2;
        }
    }

    // epilogue: broadcast h_511, lane 7 captures, flush octet [504..511]
    {
        float r0 = h;
        float r1 = dppf<DPP_QP   >(r0);
        float r2 = dppf<DPP_ROR4 >(r0);
        float r3 = dppf<DPP_ROR4 >(r1);
        float r4 = dppf<DPP_ROR8 >(r0);
        float r5 = dppf<DPP_ROR8 >(r1);
        float r6 = dppf<DPP_ROR12>(r0);
        float r7 = dppf<DPP_ROR12>(r1);
        bool cap = (j == 7);
        hh[0] = cap ? r0 : hh[0];
        hh[1] = cap ? r1 : hh[1];
        hh[2] = cap ? r2 : hh[2];
        hh[3] = cap ? r3 : hh[3];
        hh[4] = cap ? r4 : hh[4];
        hh[5] = cap ? r5 : hh[5];
        hh[6] = cap ? r6 : hh[6];
        hh[7] = cap ? r7 : hh[7];
        flush();
    }
}

// ---------------------------------------------------------------------------
// Launch: inputs 0 tokens 1 emb 2 W 3 U 4 b 5 Wd 6 bd; out f32 B*T*10.
// d_ws: 12800 B for embW (rewritten every call -> deterministic).
// ---------------------------------------------------------------------------
extern "C" void kernel_launch(void* const* d_in, const int* in_sizes, int n_in,
                              void* d_out, int out_size, void* d_ws, size_t ws_size,
                              hipStream_t stream) {
    const int*   tokens = (const int*)d_in[0];
    const float* emb    = (const float*)d_in[1];
    const float* W      = (const float*)d_in[2];
    const float* U      = (const float*)d_in[3];
    const float* b      = (const float*)d_in[4];
    const float* Wd     = (const float*)d_in[5];
    const float* bd     = (const float*)d_in[6];
    float* outp = (float*)d_out;
    float* embw = (float*)d_ws;

    embw_kernel<<<dim3(VOCABN), dim3(32), 0, stream>>>(emb, W, b, embw);
    lstm_kernel<<<dim3(BATCHN / 8), dim3(64), 0, stream>>>(tokens, embw, U, Wd, bd, outp);
}

// Round 3
// 88.301 us; speedup vs baseline: 1.7379x; 1.5255x over previous
//
#include <hip/hip_runtime.h>

// Problem constants (match reference)
#define VOCABN 100
#define EMBEDN 16
#define STATEN 7
#define OUTN   10
#define BATCHN 4096
#define SEQT   512
#define L2E 1.44269504088896340736f

// v_exp_f32 / v_rcp_f32 saturate correctly at inf/0 -> sigmoid/tanh forms
// below are exact at the extremes. No Newton step (v_rcp ~1 ulp).
__device__ __forceinline__ float fexp2(float x){ float r; asm("v_exp_f32 %0, %1":"=v"(r):"v"(x)); return r; }
__device__ __forceinline__ float frcp (float x){ float r; asm("v_rcp_f32 %0, %1":"=v"(r):"v"(x)); return r; }

// DPP helpers. row_ror:n = 0x120+n (16-lane ring, parity-preserving for even n);
// quad_perm [1,0,3,2] = 0xB1 (lane^1, parity-partner exchange).
template<int C> __device__ __forceinline__ int dppi(int x){
  return __builtin_amdgcn_update_dpp(0, x, C, 0xF, 0xF, true);
}
template<int C> __device__ __forceinline__ float dppf(float x){
  return __int_as_float(__builtin_amdgcn_update_dpp(0, __float_as_int(x), C, 0xF, 0xF, true));
}

// ---------------------------------------------------------------------------
// Kernel A: embW2[v][pos] = float2 of pre-scaled gate pre-activations.
// pos = s*2+p; p0 -> gates (i,f), p1 -> gates (g,o).
// scale: gates i,f,o: -log2(e)  (sigmoid via rcp(1+exp2(z')))
//        gate  g:     +2log2(e) (tanh via 1-2rcp(1+exp2(z')))
// Pad state s=7 (pos 14,15) -> zeros.
// ---------------------------------------------------------------------------
__global__ void embw_kernel(const float* __restrict__ emb, const float* __restrict__ W,
                            const float* __restrict__ b, float* __restrict__ embw){
  int v = blockIdx.x, j = threadIdx.x;          // j 0..31: one float each
  int pos = j >> 1, g2 = j & 1;
  int s = pos >> 1, p = pos & 1, gate = p*2 + g2;
  float val = 0.0f;
  if (s < STATEN) {
    int col = gate*STATEN + s;
    val = b[col];
    #pragma unroll
    for (int e = 0; e < EMBEDN; ++e) val = fmaf(emb[v*EMBEDN+e], W[e*28+col], val);
    val *= (gate == 2) ? (2.0f*L2E) : (-L2E);
  }
  embw[v*32 + pos*2 + g2] = val;
}

// ---------------------------------------------------------------------------
// Kernel B: fused LSTM + dense + softmax. 64 threads = 1 wave = 4 chains of
// 16 lanes (one DPP row each). Lane (s = pos>>1, p = pos&1) computes gate
// columns (i,f) [p0] or (g,o) [p1] for state s; pad lanes s=7 compute zeros.
// Cell state kept in C = 2*log2e*c domain (no muls on the tanh paths).
// h broadcast: 7 depth-1 row_ror DPP movs; sigma (which state lands in r_k)
// discovered at init by pushing the lane's state id through the same net,
// U/Wd coefficients loaded pre-permuted (and pre-scaled).
// Dense+softmax: lane (s,p) computes outputs p*5..p*5+4 of timestep
// (octet base + s), staged branch-free across the 8 steps of the next octet.
// LDS only for prefetch (embW row depth-2 queue, tokens depth-3) -> off-path.
// ---------------------------------------------------------------------------
__global__ void __launch_bounds__(64,1)
lstm_kernel(const int* __restrict__ tokens, const float* __restrict__ embw,
            const float* __restrict__ U, const float* __restrict__ Wd,
            const float* __restrict__ bdv, float* __restrict__ out){
  __shared__ float embW_s[VOCABN*32];   // 12.8 KB
  __shared__ int   tok_s[4*520];        // 4 chains, stride 520 (+pads for over-read)

  const int L = threadIdx.x;
  const int b0 = blockIdx.x*4;

  for (int i=L;i<VOCABN*8;i+=64) ((float4*)embW_s)[i]=((const float4*)embw)[i];
  for (int i=L;i<512;i+=64){ int r=i>>7,c4=i&127;
    int4 v=((const int4*)(tokens+(size_t)(b0+r)*SEQT))[c4];
    *((int4*)&tok_s[r*520+c4*4])=v; }
  if (L<4){ tok_s[L*520+512]=0; tok_s[L*520+513]=0; tok_s[L*520+514]=0; }
  __syncthreads();

  const int pos=L&15, ch=L>>4, s=pos>>1, p=pos&1;

  // sigma discovery: run own state id through the exact broadcast net
  int sg[8];
  sg[0]=s;
  sg[1]=dppi<0x122>(s); sg[2]=dppi<0x124>(s); sg[3]=dppi<0x126>(s);
  sg[4]=dppi<0x128>(s); sg[5]=dppi<0x12A>(s); sg[6]=dppi<0x12C>(s); sg[7]=dppi<0x12E>(s);

  // recurrent weights, pre-permuted by sigma, pre-scaled per gate
  float Uc0[8], Uc1[8];
  {
    const int gA=p*2, gB=p*2+1;
    const float sA = (gA==2)?(2.0f*L2E):(-L2E);
    const float sB = (gB==2)?(2.0f*L2E):(-L2E);
    #pragma unroll
    for (int k=0;k<8;++k){
      int sk=sg[k]; bool vld=(sk<STATEN)&&(s<STATEN);
      Uc0[k]= vld ? U[sk*28+gA*7+s]*sA : 0.0f;
      Uc1[k]= vld ? U[sk*28+gB*7+s]*sB : 0.0f;
    }
  }
  // dense weights (half per parity), pre-permuted, pre-scaled by log2e
  float Wdc[8][5], bdr[5];
  #pragma unroll
  for (int k=0;k<8;++k){ int sk=sg[k];
    #pragma unroll
    for (int o=0;o<5;++o) Wdc[k][o] = (sk<STATEN)? Wd[sk*10+p*5+o]*L2E : 0.0f; }
  #pragma unroll
  for (int o=0;o<5;++o) bdr[o]=bdv[p*5+o]*L2E;

  const int* trow=&tok_s[ch*520];
  float* outp = out + ((size_t)(b0+ch)*SEQT + s)*OUTN + p*5;

  float hh[8], hc[8], lg[5], ee[5];
  #pragma unroll
  for (int k=0;k<8;++k){ hh[k]=0.0f; hc[k]=0.0f; }
  #pragma unroll
  for (int o=0;o<5;++o){ lg[o]=0.0f; ee[o]=0.0f; }
  float mx=0.0f, rs=0.0f;

  // prefetch queues: embW depth-2, token depth-3
  int tk2 = trow[2];
  float2 pf0 = *(const float2*)&embW_s[trow[0]*32+pos*2];
  float2 pf1 = *(const float2*)&embW_s[trow[1]*32+pos*2];
  float Cc=0.0f, h=0.0f;

  for (int t8=0;t8<SEQT;t8+=8){
    #pragma unroll
    for (int u=0;u<8;++u){
      // issue prefetches (consumed 2 / 1 iterations later)
      float2 pf2 = *(const float2*)&embW_s[tk2*32+pos*2];
      int tk3 = trow[t8+u+3];

      // broadcast h_{t-1} across the 16-lane chain (depth-1 DPP net)
      float r0=h;
      float r1=dppf<0x122>(h), r2=dppf<0x124>(h), r3=dppf<0x126>(h);
      float r4=dppf<0x128>(h), r5=dppf<0x12A>(h), r6=dppf<0x12C>(h), r7=dppf<0x12E>(h);

      // lane-pair of state sidx captures the h-vector of timestep t-1 when u == sidx+1 (mod 8)
      bool cap = (s==((u+7)&7));
      hh[0]=cap?r0:hh[0]; hh[1]=cap?r1:hh[1]; hh[2]=cap?r2:hh[2]; hh[3]=cap?r3:hh[3];
      hh[4]=cap?r4:hh[4]; hh[5]=cap?r5:hh[5]; hh[6]=cap?r6:hh[6]; hh[7]=cap?r7:hh[7];

      // ---- branch-free flush pipeline for the PREVIOUS octet (stage per u) ----
      if (u==0){ hc[0]=hh[0];hc[1]=hh[1];hc[2]=hh[2];hc[3]=hh[3];
                 hc[4]=hh[4];hc[5]=hh[5];hc[6]=hh[6];hc[7]=hh[7]; }
      if (u==1){
        float a0=bdr[0], a1=bdr[1];
        #pragma unroll
        for (int k=0;k<8;++k){ a0=__builtin_fmaf(hc[k],Wdc[k][0],a0);
                               a1=__builtin_fmaf(hc[k],Wdc[k][1],a1); }
        lg[0]=a0; lg[1]=a1; }
      if (u==2){
        float a2=bdr[2], a3=bdr[3];
        #pragma unroll
        for (int k=0;k<8;++k){ a2=__builtin_fmaf(hc[k],Wdc[k][2],a2);
                               a3=__builtin_fmaf(hc[k],Wdc[k][3],a3); }
        lg[2]=a2; lg[3]=a3; }
      if (u==3){
        float a4=bdr[4];
        #pragma unroll
        for (int k=0;k<8;++k) a4=__builtin_fmaf(hc[k],Wdc[k][4],a4);
        lg[4]=a4; }
      if (u==4){
        float m=fmaxf(fmaxf(fmaxf(lg[0],lg[1]),fmaxf(lg[2],lg[3])),lg[4]);
        mx=fmaxf(m, dppf<0xB1>(m)); }              // combine with parity partner
      if (u==5){
        ee[0]=fexp2(lg[0]-mx); ee[1]=fexp2(lg[1]-mx); ee[2]=fexp2(lg[2]-mx);
        ee[3]=fexp2(lg[3]-mx); ee[4]=fexp2(lg[4]-mx); }
      if (u==6){
        float sm=((ee[0]+ee[1])+(ee[2]+ee[3]))+ee[4];
        rs=frcp(sm + dppf<0xB1>(sm)); }
      if (u==7){
        if (t8>0){
          outp[0]=ee[0]*rs; outp[1]=ee[1]*rs; outp[2]=ee[2]*rs;
          outp[3]=ee[3]*rs; outp[4]=ee[4]*rs;
          outp += 8*OUTN;
        } }

      // ---- z = embW'[tok] + h @ U' (tree-sum, pre-scaled) ----
      float zA, zB;
      { float q0=__builtin_fmaf(r0,Uc0[0],pf0.x);
        float q1=__builtin_fmaf(r1,Uc0[1], r2*Uc0[2]);
        float q2=__builtin_fmaf(r3,Uc0[3], r4*Uc0[4]);
        float q3=__builtin_fmaf(r5,Uc0[5], r6*Uc0[6]);
        zA=(q0+q1)+((q2+q3)+r7*Uc0[7]); }
      { float q0=__builtin_fmaf(r0,Uc1[0],pf0.y);
        float q1=__builtin_fmaf(r1,Uc1[1], r2*Uc1[2]);
        float q2=__builtin_fmaf(r3,Uc1[3], r4*Uc1[4]);
        float q3=__builtin_fmaf(r5,Uc1[5], r6*Uc1[6]);
        zB=(q0+q1)+((q2+q3)+r7*Uc1[7]); }

      // gates: p0: gA=i, gB=f ; p1: gA=rcp-part of g, gB=o
      float gA=frcp(1.0f+fexp2(zA));
      float gB=frcp(1.0f+fexp2(zB));
      float gg_s=__builtin_fmaf(gA,-4.0f*L2E,2.0f*L2E); // = 2L2E*tanh(zg) on p1
      float gg_x=dppf<0xB1>(gg_s);                      // p0 <- p1's gg_s
      float go_x=dppf<0xB1>(gB);                        // p0 <- p1's go
      // C = f*C + i*gg_s   (valid on p0; p1's copy bounded-garbage, never used)
      Cc=__builtin_fmaf(gB,Cc,gA*gg_x);
      float rcpC=frcp(1.0f+fexp2(Cc));                  // valid on p0
      float rcpC_x=dppf<0xB1>(rcpC);                    // p1 <- p0's
      float go_u = p ? gB     : go_x;
      float rc_u = p ? rcpC_x : rcpC;
      h = __builtin_fmaf(-2.0f*go_u, rc_u, go_u);       // h = o * tanh(c), both parities

      pf0=pf1; pf1=pf2; tk2=tk3;
    }
  }

  // ---- epilogue: capture h_511 into slot 7, flush last octet (ts 504..511) ----
  {
    float r0=h;
    float r1=dppf<0x122>(h), r2=dppf<0x124>(h), r3=dppf<0x126>(h);
    float r4=dppf<0x128>(h), r5=dppf<0x12A>(h), r6=dppf<0x12C>(h), r7=dppf<0x12E>(h);
    bool cap = (s==7);
    hh[0]=cap?r0:hh[0]; hh[1]=cap?r1:hh[1]; hh[2]=cap?r2:hh[2]; hh[3]=cap?r3:hh[3];
    hh[4]=cap?r4:hh[4]; hh[5]=cap?r5:hh[5]; hh[6]=cap?r6:hh[6]; hh[7]=cap?r7:hh[7];
    float a[5];
    #pragma unroll
    for (int o=0;o<5;++o){ a[o]=bdr[o];
      #pragma unroll
      for (int k=0;k<8;++k) a[o]=__builtin_fmaf(hh[k],Wdc[k][o],a[o]); }
    float m=fmaxf(fmaxf(fmaxf(a[0],a[1]),fmaxf(a[2],a[3])),a[4]);
    m=fmaxf(m, dppf<0xB1>(m));
    float e0=fexp2(a[0]-m), e1=fexp2(a[1]-m), e2=fexp2(a[2]-m),
          e3=fexp2(a[3]-m), e4=fexp2(a[4]-m);
    float sm=((e0+e1)+(e2+e3))+e4;
    float r=frcp(sm + dppf<0xB1>(sm));
    outp[0]=e0*r; outp[1]=e1*r; outp[2]=e2*r; outp[3]=e3*r; outp[4]=e4*r;
  }
}

// ---------------------------------------------------------------------------
// inputs: 0 tokens 1 emb 2 W 3 U 4 b 5 Wd 6 bd ; out f32 B*T*10.
// d_ws: 12800 B for the pre-scaled embW table (rewritten every call).
// ---------------------------------------------------------------------------
extern "C" void kernel_launch(void* const* d_in, const int* in_sizes, int n_in,
                              void* d_out, int out_size, void* d_ws, size_t ws_size,
                              hipStream_t stream) {
  const int*   tokens = (const int*)d_in[0];
  const float* emb    = (const float*)d_in[1];
  const float* W      = (const float*)d_in[2];
  const float* U      = (const float*)d_in[3];
  const float* b      = (const float*)d_in[4];
  const float* Wd     = (const float*)d_in[5];
  const float* bd     = (const float*)d_in[6];
  float* outp = (float*)d_out;
  float* embw = (float*)d_ws;

  embw_kernel<<<dim3(VOCABN), dim3(32), 0, stream>>>(emb, W, b, embw);
  lstm_kernel<<<dim3(BATCHN/4), dim3(64), 0, stream>>>(tokens, embw, U, Wd, bd, outp);
}